// Round 1
// baseline (447.405 us; speedup 1.0000x reference)
//
#include <hip/hip_runtime.h>

// LightGCN 2-layer propagation on MI355X — R10: unified embedding table +
// full-width pipelined gathers.
//
// R9 post-mortem: k_gh1 70 us with HBM 42.6%, VALUBusy 22.5%, Occ 76% —
// neither pipe saturated => latency-bound. Chain per iter: adj load ->
// addr -> 128 B gather -> vmcnt -> acc, with the user/item split cutting
// each node walk into two short loops (4.4 + 2.2 trips/slot).
// R10:
//  (1) concat user+item tables into `out` up front (fused into k_count) ->
//      ONE base pointer, raw neighbor ids, single loop per node;
//      k_fill_local loses the segregation histogram/cursor pass.
//  (2) full-width (64-col, 256 B/row) gathers when ws_size allows: 2 gather
//      dispatches instead of 4 (adj walked 2x not 4x, addr math halved per
//      byte, 2x bytes in flight per chain). Fallback: 32-col halves using
//      column independence (layer h reads only cols h of emb), half buffer
//      reused, `out` holds emb until each col-half is consumed.
//  (3) 1-deep software pipeline: prefetch next adj + next row while
//      accumulating previous row -> waitcnt covers loads issued one
//      iteration earlier.

#define NUM_USERS 100000
#define NUM_ITEMS 50000
#define N_NODES   150000
#define NUM_EDGES 2000000
#define EMB_D     64

#define BSH    8                                   // 256 nodes per bucket
#define BNODES 256
#define NBUCK  ((N_NODES + BNODES - 1) / BNODES)   // 586
#define P      512                                 // producer blocks
#define CE     ((NUM_EDGES + P - 1) / P)           // 3907 edges per block
#define NTOT   (NBUCK * P)                         // 300032 = 293 * 1024
#define SBLK   (NTOT / 1024)                       // 293 scan blocks

#define CPYB   1536                                // concat-copy blocks
#define U4CNT  (NUM_USERS * (EMB_D / 4))           // 1.6M float4
#define T4CNT  (N_NODES   * (EMB_D / 4))           // 2.4M float4

// ---- A) per-block bucket histogram + fused emb concat into out ----
__global__ __launch_bounds__(256) void k_count_concat(const int* __restrict__ eidx,
                                                      int* __restrict__ cnt,
                                                      const float4* __restrict__ user4,
                                                      const float4* __restrict__ item4,
                                                      float4* __restrict__ out4) {
    int g = blockIdx.x, tid = threadIdx.x;
    if (g >= P) {
        // concat: out rows [0,NUM_USERS) = user, [NUM_USERS,N) = item
        int i = (g - P) * 256 + tid;
        const int stride = CPYB * 256;
        for (; i < T4CNT; i += stride)
            out4[i] = (i < U4CNT) ? user4[i] : item4[i - U4CNT];
        return;
    }
    __shared__ int hist[NBUCK];
    for (int b = tid; b < NBUCK; b += 256) hist[b] = 0;
    __syncthreads();
    int lo = g * CE, hi = min(NUM_EDGES, lo + CE);
    for (int j = lo + tid; j < hi; j += 256) {
        int r = eidx[j], c = eidx[NUM_EDGES + j];
        atomicAdd(&hist[r >> BSH], 1);
        atomicAdd(&hist[c >> BSH], 1);
    }
    __syncthreads();
    for (int b = tid; b < NBUCK; b += 256) cnt[b * P + g] = hist[b];
}

// ---- B1) local exclusive scan: 1024 elems/block (256 thr x 4) ----
__global__ __launch_bounds__(256) void k_scan1(int* __restrict__ cnt,
                                               int* __restrict__ blocksums) {
    __shared__ int lds[256];
    int base = blockIdx.x * 1024 + threadIdx.x * 4;
    int v0 = cnt[base + 0], v1 = cnt[base + 1], v2 = cnt[base + 2], v3 = cnt[base + 3];
    int t = v0 + v1 + v2 + v3;
    lds[threadIdx.x] = t;
    __syncthreads();
    int val = t;
    for (int off = 1; off < 256; off <<= 1) {
        int add = (threadIdx.x >= off) ? lds[threadIdx.x - off] : 0;
        __syncthreads();
        val += add;
        lds[threadIdx.x] = val;
        __syncthreads();
    }
    int run = val - t;
    cnt[base + 0] = run; run += v0;
    cnt[base + 1] = run; run += v1;
    cnt[base + 2] = run; run += v2;
    cnt[base + 3] = run;
    if (threadIdx.x == 255) blocksums[blockIdx.x] = val;
}

// ---- B2) 1-block exclusive scan of 293 partials ----
__global__ __launch_bounds__(512) void k_scan2(const int* __restrict__ blocksums,
                                               int* __restrict__ blockoffs) {
    __shared__ int lds[512];
    int t = threadIdx.x;
    int v = (t < SBLK) ? blocksums[t] : 0;
    lds[t] = v;
    __syncthreads();
    int val = v;
    for (int off = 1; off < 512; off <<= 1) {
        int add = (t >= off) ? lds[t - off] : 0;
        __syncthreads();
        val += add;
        lds[t] = val;
        __syncthreads();
    }
    if (t < SBLK) blockoffs[t] = val - v;
}

// ---- B3) add block offsets ----
__global__ __launch_bounds__(256) void k_scan3(int* __restrict__ cnt,
                                               const int* __restrict__ blockoffs) {
    int i = blockIdx.x * blockDim.x + threadIdx.x;
    if (i < NTOT) cnt[i] += blockoffs[i >> 10];
}

// ---- C) scatter entries into private (bucket, block) slices ----
__global__ __launch_bounds__(256) void k_scatter(const int* __restrict__ eidx,
                                                 const int* __restrict__ cofs,
                                                 unsigned* __restrict__ entries) {
    __shared__ int lcur[NBUCK];
    int g = blockIdx.x, tid = threadIdx.x;
    for (int b = tid; b < NBUCK; b += 256) lcur[b] = cofs[b * P + g];
    __syncthreads();
    int lo = g * CE, hi = min(NUM_EDGES, lo + CE);
    for (int j = lo + tid; j < hi; j += 256) {
        int r = eidx[j], c = eidx[NUM_EDGES + j];
        int p = atomicAdd(&lcur[r >> BSH], 1);
        entries[p] = ((unsigned)(r & 255) << 18) | (unsigned)c;  // raw id, <2^18
        int q = atomicAdd(&lcur[c >> BSH], 1);
        entries[q] = ((unsigned)(c & 255) << 18) | (unsigned)r;
    }
}

// ---- D) per-bucket exact CSR (no user/item segregation — raw ids) ----
__global__ __launch_bounds__(512) void k_fill_local(const unsigned* __restrict__ entries,
                                                    const int* __restrict__ cofs,
                                                    int* __restrict__ adj,
                                                    int* __restrict__ start_g,
                                                    int* __restrict__ deg_g) {
    __shared__ int lh[BNODES];    // degree per local node
    __shared__ int lsc[BNODES];   // scan scratch
    __shared__ int cur[BNODES];
    int b = blockIdx.x, tid = threadIdx.x;
    int gbase = cofs[b * P];
    int gnext = (b + 1 < NBUCK) ? cofs[(b + 1) * P] : 2 * NUM_EDGES;
    int cnt = gnext - gbase;
    const unsigned* eb = entries + gbase;

    if (tid < BNODES) lh[tid] = 0;
    __syncthreads();
    for (int j = tid; j < cnt; j += 512) atomicAdd(&lh[eb[j] >> 18], 1);
    __syncthreads();

    if (tid < BNODES) lsc[tid] = lh[tid];
    __syncthreads();
    for (int off = 1; off < BNODES; off <<= 1) {
        int add = 0;
        if (tid < BNODES && tid >= off) add = lsc[tid - off];
        __syncthreads();
        if (tid < BNODES) lsc[tid] += add;
        __syncthreads();
    }

    if (tid < BNODES) {
        int deg = lh[tid];
        int st = lsc[tid] - deg;                  // exclusive
        int node = (b << BSH) + tid;
        if (node < N_NODES) {
            start_g[node] = gbase + st;
            deg_g[node] = deg;
        }
        cur[tid] = st;
    }
    __syncthreads();

    for (int j = tid; j < cnt; j += 512) {
        unsigned e = eb[j];
        int p = atomicAdd(&cur[e >> 18], 1);
        adj[(size_t)gbase + p] = (int)(e & 0x3FFFF);
    }
}

// ---- E) pipelined gather: 32 lanes/node = 4 slots x 8 lanes ----
// W=64: lane covers floats [sub*8, sub*8+8) of a 256 B row (2x float4)
// W=32: lane covers floats [sub*4, sub*4+4) (1x float4)
// LS/LD: src/dst row stride in floats (compile-time -> shift addressing).
// 1-deep software pipeline: next adj + next row issued before accumulating
// the previous row, so per-iter waitcnt covers loads from one iter ago.
template <int W, int LS, int LD>
__global__ __launch_bounds__(256) void k_gather(const int* __restrict__ adj,
                                                const int* __restrict__ start_g,
                                                const int* __restrict__ deg_g,
                                                const float* __restrict__ src,
                                                float* __restrict__ dst) {
    int gid = blockIdx.x * blockDim.x + threadIdx.x;
    int node = gid >> 5;
    if (node >= N_NODES) return;
    int grp = threadIdx.x & 31;
    int slot = grp >> 3;          // 0..3 entry slot
    int sub = grp & 7;            // lane column group

    int start = start_g[node];
    int end = start + deg_g[node];
    const float* base = src + sub * (W / 8);

    float4 aL = make_float4(0.f, 0.f, 0.f, 0.f);
    float4 aH = make_float4(0.f, 0.f, 0.f, 0.f);

    int j = start + slot;
    if (j < end) {
        int n = adj[j];
        j += 4;
        int jp = (j < end) ? j : start;     // safe dummy prefetch addr
        int nn = adj[jp];
        const float* p = base + (size_t)(n * LS);
        float4 c0 = *(const float4*)p;
        float4 c1 = make_float4(0.f, 0.f, 0.f, 0.f);
        if constexpr (W == 64) c1 = *(const float4*)(p + 4);
        while (j < end) {
            j += 4;
            jp = (j < end) ? j : start;
            int n2 = adj[jp];               // prefetch next adj
            const float* q = base + (size_t)(nn * LS);
            float4 d0 = *(const float4*)q;  // issue next row
            float4 d1 = make_float4(0.f, 0.f, 0.f, 0.f);
            if constexpr (W == 64) d1 = *(const float4*)(q + 4);
            aL.x += c0.x; aL.y += c0.y; aL.z += c0.z; aL.w += c0.w;  // consume prev
            if constexpr (W == 64) { aH.x += c1.x; aH.y += c1.y; aH.z += c1.z; aH.w += c1.w; }
            c0 = d0; c1 = d1; nn = n2;
        }
        aL.x += c0.x; aL.y += c0.y; aL.z += c0.z; aL.w += c0.w;
        if constexpr (W == 64) { aH.x += c1.x; aH.y += c1.y; aH.z += c1.z; aH.w += c1.w; }
    }

    // reduce across the 4 slots (lanes xor 8, 16 within the 32-lane group)
    aL.x += __shfl_xor(aL.x, 8);  aL.y += __shfl_xor(aL.y, 8);
    aL.z += __shfl_xor(aL.z, 8);  aL.w += __shfl_xor(aL.w, 8);
    aL.x += __shfl_xor(aL.x, 16); aL.y += __shfl_xor(aL.y, 16);
    aL.z += __shfl_xor(aL.z, 16); aL.w += __shfl_xor(aL.w, 16);
    if constexpr (W == 64) {
        aH.x += __shfl_xor(aH.x, 8);  aH.y += __shfl_xor(aH.y, 8);
        aH.z += __shfl_xor(aH.z, 8);  aH.w += __shfl_xor(aH.w, 8);
        aH.x += __shfl_xor(aH.x, 16); aH.y += __shfl_xor(aH.y, 16);
        aH.z += __shfl_xor(aH.z, 16); aH.w += __shfl_xor(aH.w, 16);
    }

    if (slot == 0) {
        float* o = dst + (size_t)node * LD + sub * (W / 8);
        *(float4*)o = make_float4(0.5f * aL.x, 0.5f * aL.y, 0.5f * aL.z, 0.5f * aL.w);
        if constexpr (W == 64)
            *(float4*)(o + 4) = make_float4(0.5f * aH.x, 0.5f * aH.y, 0.5f * aH.z, 0.5f * aH.w);
    }
}

extern "C" void kernel_launch(void* const* d_in, const int* in_sizes, int n_in,
                              void* d_out, int out_size, void* d_ws, size_t ws_size,
                              hipStream_t stream) {
    const int*   eidx = (const int*)d_in[0];     // [2, NUM_EDGES]
    const float* user = (const float*)d_in[1];   // [NUM_USERS, 64]
    const float* item = (const float*)d_in[2];   // [NUM_ITEMS, 64]
    float*       out  = (float*)d_out;           // [N_NODES, 64]

    auto al = [](size_t x) { return (x + 255) & ~(size_t)255; };
    size_t sz_inter   = (size_t)N_NODES * 64 * sizeof(float);      // 38.4 MB
    size_t sz_half    = (size_t)N_NODES * 32 * sizeof(float);      // 19.2 MB
    size_t sz_entries = (size_t)2 * NUM_EDGES * sizeof(unsigned);  // 16 MB
    size_t sz_adj     = (size_t)2 * NUM_EDGES * sizeof(int);       // 16 MB
    size_t need_big = al(sz_inter) + al(sz_adj) + 2 * al((size_t)N_NODES * 4)
                    + al((size_t)NTOT * 4) + 2 * al((size_t)SBLK * 4);   // ~56.8 MB
    bool big = ws_size >= need_big;

    char* ws = (char*)d_ws;
    size_t off = 0;
    auto alloc = [&](size_t bytes) {
        char* p = ws + off;
        off += (bytes + 255) & ~(size_t)255;
        return p;
    };
    // union: entries (dead after k_fill_local) / inter (big) or half (small)
    size_t sz_uni = big ? sz_inter : (sz_half > sz_entries ? sz_half : sz_entries);
    char*     uni     = alloc(sz_uni);
    unsigned* entries = (unsigned*)uni;
    float*    inter   = (float*)uni;           // big path
    float*    half    = (float*)uni;           // small path
    int*      adj     = (int*)alloc(sz_adj);
    int*      start_g = (int*)alloc((size_t)N_NODES * sizeof(int));
    int*      deg_g   = (int*)alloc((size_t)N_NODES * sizeof(int));
    int*      cnt     = (int*)alloc((size_t)NTOT * sizeof(int));
    int*      bsums   = (int*)alloc((size_t)SBLK * sizeof(int));
    int*      boffs   = (int*)alloc((size_t)SBLK * sizeof(int));

    // CSR build (+ fused emb concat into out)
    k_count_concat<<<P + CPYB, 256, 0, stream>>>(eidx, cnt, (const float4*)user,
                                                 (const float4*)item, (float4*)out);
    k_scan1<<<SBLK, 256, 0, stream>>>(cnt, bsums);
    k_scan2<<<1, 512, 0, stream>>>(bsums, boffs);
    k_scan3<<<(NTOT + 255) / 256, 256, 0, stream>>>(cnt, boffs);
    k_scatter<<<P, 256, 0, stream>>>(eidx, cnt, entries);
    k_fill_local<<<NBUCK, 512, 0, stream>>>(entries, cnt, adj, start_g, deg_g);

    const int ggh = ((N_NODES * 32) + 255) / 256;  // 18750 blocks
    if (big) {
        // full-width: emb(out) -> inter -> out
        k_gather<64, 64, 64><<<ggh, 256, 0, stream>>>(adj, start_g, deg_g, out, inter);
        k_gather<64, 64, 64><<<ggh, 256, 0, stream>>>(adj, start_g, deg_g, inter, out);
    } else {
        // column-independent halves; out holds emb cols until consumed.
        // h=0: read emb cols 0-31 (out), write half; then half -> out cols 0-31
        k_gather<32, 64, 32><<<ggh, 256, 0, stream>>>(adj, start_g, deg_g, out + 0, half);
        k_gather<32, 32, 64><<<ggh, 256, 0, stream>>>(adj, start_g, deg_g, half, out + 0);
        // h=1: emb cols 32-63 still untouched in out
        k_gather<32, 64, 32><<<ggh, 256, 0, stream>>>(adj, start_g, deg_g, out + 32, half);
        k_gather<32, 32, 64><<<ggh, 256, 0, stream>>>(adj, start_g, deg_g, half, out + 32);
    }
}

// Round 2
// 307.460 us; speedup vs baseline: 1.4552x; 1.4552x over previous
//
#include <hip/hip_runtime.h>
#include <hip/hip_fp16.h>

// LightGCN 2-layer propagation on MI355X — R11: fp16 gather operands.
//
// R10 post-mortem: full-width (256 B) gathers were NEUTRAL vs R9's 128 B
// halves — both sustain ~7.5 TB/s logical L2-read (R9: 512 MB/70us, R10:
// 1.02 GB/135us) with VALUBusy 22%, HBM fill 47%. Gather time scales with
// BYTES, not dispatches/addr-math/pipeline depth => random-row fill wall.
// R11: halve the bytes. Table + layer-1 intermediate stored as fp16
// (128 B rows); accumulation stays fp32 (err ~0.016 max vs 0.125 tol).
//  - fp16 concat table lives in out[0 .. 19.2MB) (dead until layer-2 write)
//  - inter_h (fp16) unions with entries in ws; ws back to ~39 MB, no branch
//  - k_scan3 folded into k_scatter / k_fill_local (boffs added on the fly)

#define NUM_USERS 100000
#define NUM_ITEMS 50000
#define N_NODES   150000
#define NUM_EDGES 2000000
#define EMB_D     64

#define BSH    8                                   // 256 nodes per bucket
#define BNODES 256
#define NBUCK  ((N_NODES + BNODES - 1) / BNODES)   // 586
#define P      512                                 // producer blocks
#define CE     ((NUM_EDGES + P - 1) / P)           // 3907 edges per block
#define NTOT   (NBUCK * P)                         // 300032 = 293 * 1024
#define SBLK   (NTOT / 1024)                       // 293 scan blocks

#define CPYB   1024                                // concat-convert blocks
#define H8CNT  (N_NODES * (EMB_D / 8))             // 1.2M 16-byte chunks
#define UF4    (NUM_USERS * (EMB_D / 4))           // user float4 count

struct alignas(16) h8vec { __half2 h[4]; };        // 8 halves = 16 B

// ---- A) per-block bucket histogram + fused fp32->fp16 concat ----
__global__ __launch_bounds__(256) void k_count_concat(const int* __restrict__ eidx,
                                                      int* __restrict__ cnt,
                                                      const float4* __restrict__ user4,
                                                      const float4* __restrict__ item4,
                                                      h8vec* __restrict__ tab) {
    int g = blockIdx.x, tid = threadIdx.x;
    if (g >= P) {
        int i = (g - P) * 256 + tid;
        const int stride = CPYB * 256;
        for (; i < H8CNT; i += stride) {
            const float4* s = (i * 2 < UF4) ? (user4 + (size_t)i * 2)
                                            : (item4 + ((size_t)i * 2 - UF4));
            float4 a = s[0], b = s[1];
            h8vec o;
            o.h[0] = __floats2half2_rn(a.x, a.y);
            o.h[1] = __floats2half2_rn(a.z, a.w);
            o.h[2] = __floats2half2_rn(b.x, b.y);
            o.h[3] = __floats2half2_rn(b.z, b.w);
            tab[i] = o;
        }
        return;
    }
    __shared__ int hist[NBUCK];
    for (int b = tid; b < NBUCK; b += 256) hist[b] = 0;
    __syncthreads();
    int lo = g * CE, hi = min(NUM_EDGES, lo + CE);
    for (int j = lo + tid; j < hi; j += 256) {
        int r = eidx[j], c = eidx[NUM_EDGES + j];
        atomicAdd(&hist[r >> BSH], 1);
        atomicAdd(&hist[c >> BSH], 1);
    }
    __syncthreads();
    for (int b = tid; b < NBUCK; b += 256) cnt[b * P + g] = hist[b];
}

// ---- B1) local exclusive scan: 1024 elems/block (256 thr x 4) ----
__global__ __launch_bounds__(256) void k_scan1(int* __restrict__ cnt,
                                               int* __restrict__ blocksums) {
    __shared__ int lds[256];
    int base = blockIdx.x * 1024 + threadIdx.x * 4;
    int v0 = cnt[base + 0], v1 = cnt[base + 1], v2 = cnt[base + 2], v3 = cnt[base + 3];
    int t = v0 + v1 + v2 + v3;
    lds[threadIdx.x] = t;
    __syncthreads();
    int val = t;
    for (int off = 1; off < 256; off <<= 1) {
        int add = (threadIdx.x >= off) ? lds[threadIdx.x - off] : 0;
        __syncthreads();
        val += add;
        lds[threadIdx.x] = val;
        __syncthreads();
    }
    int run = val - t;
    cnt[base + 0] = run; run += v0;
    cnt[base + 1] = run; run += v1;
    cnt[base + 2] = run; run += v2;
    cnt[base + 3] = run;
    if (threadIdx.x == 255) blocksums[blockIdx.x] = val;
}

// ---- B2) 1-block exclusive scan of 293 partials ----
__global__ __launch_bounds__(512) void k_scan2(const int* __restrict__ blocksums,
                                               int* __restrict__ blockoffs) {
    __shared__ int lds[512];
    int t = threadIdx.x;
    int v = (t < SBLK) ? blocksums[t] : 0;
    lds[t] = v;
    __syncthreads();
    int val = v;
    for (int off = 1; off < 512; off <<= 1) {
        int add = (t >= off) ? lds[t - off] : 0;
        __syncthreads();
        val += add;
        lds[t] = val;
        __syncthreads();
    }
    if (t < SBLK) blockoffs[t] = val - v;
}

// ---- C) scatter entries into private (bucket, block) slices ----
// global offset = cnt[i] + boffs[i >> 10]  (scan3 folded in)
__global__ __launch_bounds__(256) void k_scatter(const int* __restrict__ eidx,
                                                 const int* __restrict__ cofs,
                                                 const int* __restrict__ boffs,
                                                 unsigned* __restrict__ entries) {
    __shared__ int lcur[NBUCK];
    int g = blockIdx.x, tid = threadIdx.x;
    for (int b = tid; b < NBUCK; b += 256) {
        int idx = b * P + g;
        lcur[b] = cofs[idx] + boffs[idx >> 10];
    }
    __syncthreads();
    int lo = g * CE, hi = min(NUM_EDGES, lo + CE);
    for (int j = lo + tid; j < hi; j += 256) {
        int r = eidx[j], c = eidx[NUM_EDGES + j];
        int p = atomicAdd(&lcur[r >> BSH], 1);
        entries[p] = ((unsigned)(r & 255) << 18) | (unsigned)c;  // raw id < 2^18
        int q = atomicAdd(&lcur[c >> BSH], 1);
        entries[q] = ((unsigned)(c & 255) << 18) | (unsigned)r;
    }
}

// ---- D) per-bucket exact CSR ----
__global__ __launch_bounds__(512) void k_fill_local(const unsigned* __restrict__ entries,
                                                    const int* __restrict__ cofs,
                                                    const int* __restrict__ boffs,
                                                    int* __restrict__ adj,
                                                    int* __restrict__ start_g,
                                                    int* __restrict__ deg_g) {
    __shared__ int lh[BNODES];
    __shared__ int lsc[BNODES];
    __shared__ int cur[BNODES];
    int b = blockIdx.x, tid = threadIdx.x;
    int i0 = b * P;
    int gbase = cofs[i0] + boffs[i0 >> 10];
    int gnext = 2 * NUM_EDGES;
    if (b + 1 < NBUCK) {
        int i1 = (b + 1) * P;
        gnext = cofs[i1] + boffs[i1 >> 10];
    }
    int cnt = gnext - gbase;
    const unsigned* eb = entries + gbase;

    if (tid < BNODES) lh[tid] = 0;
    __syncthreads();
    for (int j = tid; j < cnt; j += 512) atomicAdd(&lh[eb[j] >> 18], 1);
    __syncthreads();

    if (tid < BNODES) lsc[tid] = lh[tid];
    __syncthreads();
    for (int off = 1; off < BNODES; off <<= 1) {
        int add = 0;
        if (tid < BNODES && tid >= off) add = lsc[tid - off];
        __syncthreads();
        if (tid < BNODES) lsc[tid] += add;
        __syncthreads();
    }

    if (tid < BNODES) {
        int deg = lh[tid];
        int st = lsc[tid] - deg;                  // exclusive
        int node = (b << BSH) + tid;
        if (node < N_NODES) {
            start_g[node] = gbase + st;
            deg_g[node] = deg;
        }
        cur[tid] = st;
    }
    __syncthreads();

    for (int j = tid; j < cnt; j += 512) {
        unsigned e = eb[j];
        int p = atomicAdd(&cur[e >> 18], 1);
        adj[(size_t)gbase + p] = (int)(e & 0x3FFFF);
    }
}

// ---- E) pipelined fp16 gather: 32 lanes/node = 4 slots x 8 lanes ----
// Row = 64 halves = 128 B; lane loads one h8vec (16 B) covering cols
// [sub*8, sub*8+8). fp32 accumulate; 1-deep software pipeline (prefetch
// next adj + next row before consuming the previous row).
template <bool OUT_HALF>
__global__ __launch_bounds__(256) void k_gather(const int* __restrict__ adj,
                                                const int* __restrict__ start_g,
                                                const int* __restrict__ deg_g,
                                                const __half* __restrict__ src,
                                                void* __restrict__ dst) {
    int gid = blockIdx.x * blockDim.x + threadIdx.x;
    int node = gid >> 5;
    if (node >= N_NODES) return;
    int grp = threadIdx.x & 31;
    int slot = grp >> 3;          // 0..3 entry slot
    int sub = grp & 7;            // column group

    int start = start_g[node];
    int end = start + deg_g[node];
    const __half* base = src + sub * 8;

    float4 aL = make_float4(0.f, 0.f, 0.f, 0.f);
    float4 aH = make_float4(0.f, 0.f, 0.f, 0.f);

    int j = start + slot;
    if (j < end) {
        int n = adj[j];
        j += 4;
        int jp = (j < end) ? j : start;     // safe dummy prefetch (deg >= 1 here)
        int nn = adj[jp];
        h8vec c = *(const h8vec*)(base + (size_t)n * EMB_D);
        while (j < end) {
            j += 4;
            jp = (j < end) ? j : start;
            int n2 = adj[jp];               // prefetch next adj
            h8vec d = *(const h8vec*)(base + (size_t)nn * EMB_D);  // next row
            float2 f0 = __half22float2(c.h[0]);
            float2 f1 = __half22float2(c.h[1]);
            float2 f2 = __half22float2(c.h[2]);
            float2 f3 = __half22float2(c.h[3]);
            aL.x += f0.x; aL.y += f0.y; aL.z += f1.x; aL.w += f1.y;
            aH.x += f2.x; aH.y += f2.y; aH.z += f3.x; aH.w += f3.y;
            c = d; nn = n2;
        }
        float2 f0 = __half22float2(c.h[0]);
        float2 f1 = __half22float2(c.h[1]);
        float2 f2 = __half22float2(c.h[2]);
        float2 f3 = __half22float2(c.h[3]);
        aL.x += f0.x; aL.y += f0.y; aL.z += f1.x; aL.w += f1.y;
        aH.x += f2.x; aH.y += f2.y; aH.z += f3.x; aH.w += f3.y;
    }

    // reduce across the 4 slots (lanes xor 8, 16 within the 32-lane group)
    aL.x += __shfl_xor(aL.x, 8);  aL.y += __shfl_xor(aL.y, 8);
    aL.z += __shfl_xor(aL.z, 8);  aL.w += __shfl_xor(aL.w, 8);
    aH.x += __shfl_xor(aH.x, 8);  aH.y += __shfl_xor(aH.y, 8);
    aH.z += __shfl_xor(aH.z, 8);  aH.w += __shfl_xor(aH.w, 8);
    aL.x += __shfl_xor(aL.x, 16); aL.y += __shfl_xor(aL.y, 16);
    aL.z += __shfl_xor(aL.z, 16); aL.w += __shfl_xor(aL.w, 16);
    aH.x += __shfl_xor(aH.x, 16); aH.y += __shfl_xor(aH.y, 16);
    aH.z += __shfl_xor(aH.z, 16); aH.w += __shfl_xor(aH.w, 16);

    if (slot == 0) {
        if constexpr (OUT_HALF) {
            h8vec o;
            o.h[0] = __floats2half2_rn(0.5f * aL.x, 0.5f * aL.y);
            o.h[1] = __floats2half2_rn(0.5f * aL.z, 0.5f * aL.w);
            o.h[2] = __floats2half2_rn(0.5f * aH.x, 0.5f * aH.y);
            o.h[3] = __floats2half2_rn(0.5f * aH.z, 0.5f * aH.w);
            ((h8vec*)dst)[(size_t)node * 8 + sub] = o;
        } else {
            float* o = (float*)dst + (size_t)node * EMB_D + sub * 8;
            *(float4*)o = make_float4(0.5f * aL.x, 0.5f * aL.y, 0.5f * aL.z, 0.5f * aL.w);
            *(float4*)(o + 4) = make_float4(0.5f * aH.x, 0.5f * aH.y, 0.5f * aH.z, 0.5f * aH.w);
        }
    }
}

extern "C" void kernel_launch(void* const* d_in, const int* in_sizes, int n_in,
                              void* d_out, int out_size, void* d_ws, size_t ws_size,
                              hipStream_t stream) {
    const int*   eidx = (const int*)d_in[0];     // [2, NUM_EDGES]
    const float* user = (const float*)d_in[1];   // [NUM_USERS, 64]
    const float* item = (const float*)d_in[2];   // [NUM_ITEMS, 64]
    float*       out  = (float*)d_out;           // [N_NODES, 64] fp32

    // fp16 concat table lives in out[0 .. 19.2 MB) — dead once layer 2 writes.
    __half* tab_h = (__half*)out;

    char* ws = (char*)d_ws;
    size_t off = 0;
    auto alloc = [&](size_t bytes) {
        char* p = ws + off;
        off += (bytes + 255) & ~(size_t)255;
        return p;
    };
    // union: entries (16 MB, dead after fill) / inter_h (19.2 MB, gathers)
    size_t sz_uni = (size_t)N_NODES * EMB_D * sizeof(__half);      // 19.2 MB
    char*     uni     = alloc(sz_uni);
    unsigned* entries = (unsigned*)uni;
    __half*   inter_h = (__half*)uni;
    int*      adj     = (int*)alloc((size_t)2 * NUM_EDGES * sizeof(int));  // 16 MB
    int*      start_g = (int*)alloc((size_t)N_NODES * sizeof(int));
    int*      deg_g   = (int*)alloc((size_t)N_NODES * sizeof(int));
    int*      cnt     = (int*)alloc((size_t)NTOT * sizeof(int));
    int*      bsums   = (int*)alloc((size_t)SBLK * sizeof(int));
    int*      boffs   = (int*)alloc((size_t)SBLK * sizeof(int));

    // CSR build (+ fused fp16 concat into out-as-table)
    k_count_concat<<<P + CPYB, 256, 0, stream>>>(eidx, cnt, (const float4*)user,
                                                 (const float4*)item, (h8vec*)tab_h);
    k_scan1<<<SBLK, 256, 0, stream>>>(cnt, bsums);
    k_scan2<<<1, 512, 0, stream>>>(bsums, boffs);
    k_scatter<<<P, 256, 0, stream>>>(eidx, cnt, boffs, entries);
    k_fill_local<<<NBUCK, 512, 0, stream>>>(entries, cnt, boffs, adj, start_g, deg_g);

    // 2-layer propagation: tab_h (in out) -> inter_h (fp16) -> out (fp32)
    const int ggh = ((N_NODES * 32) + 255) / 256;  // 18750 blocks
    k_gather<true><<<ggh, 256, 0, stream>>>(adj, start_g, deg_g, tab_h, inter_h);
    k_gather<false><<<ggh, 256, 0, stream>>>(adj, start_g, deg_g, inter_h, out);
}